// Round 8
// baseline (461.573 us; speedup 1.0000x reference)
//
#include <hip/hip_runtime.h>
#include <math.h>

// Problem constants
#define NN   2048
#define EE   8192
#define CNF  256
#define MN   16384
#define ME   65536
#define KK   1024

// Output layout (float element offsets)
#define OUT_XN   ((size_t)0)
#define OUT_L0   ((size_t)262144)
#define OUT_XE   ((size_t)1310720)
#define OUT_L1   ((size_t)3407872)
#define OUT_PM   ((size_t)70516736)
#define OUT_XN0  ((size_t)78905344)
#define OUT_XE0  ((size_t)79167488)

// Workspace layout (element offsets)
#define WS_T1N    0
#define WS_SLINN  2048
#define WS_T1E    4096
#define WS_SLINE  12288
#define WS_SCN    20480
#define WS_SCE    22528
#define WS_JOINT  30720   // dead gap 30720..32767 (2048 floats) — no ws growth
#define WS_AGGN   32768
#define WS_AGGE   34816
#define WS_LAM    43008
#define WS_IDXK   43520
#define WS_RANK   44544
#define WS_OFFS   47616
#define WS_ADJE   66176   // int[16384], PACKED: (nbr_rank<<14)|(e<<1)|dir
#define WS_KEEPE  82560   // int[8192]

#define DCAP  8
#define PWR_T 64          // 96->64: Rayleigh error (lam_i/lam_1)^128-weighted, ~1e-4 rel
#define RBAD  0xFFFFu

// native vector for nontemporal builtin (HIP float4 is a class -> rejected)
typedef float vf4 __attribute__((ext_vector_type(4)));

// =====================================================================
// Kernel A: row dots (wave per row) + zero the ws accumulators.
// =====================================================================
__global__ void k_prep(const float* __restrict__ xn, const float* __restrict__ xe,
                       const float* __restrict__ Wn0, const float* __restrict__ Wn1,
                       const float* __restrict__ We0, const float* __restrict__ We1,
                       float* __restrict__ wsf) {
    if (blockIdx.x == 0) {   // zero accumulators (AGGN, AGGE) + joint
        for (int i = threadIdx.x; i < 2048; i += 256) wsf[WS_AGGN + i] = 0.f;
        for (int i = threadIdx.x; i < 8192; i += 256) wsf[WS_AGGE + i] = 0.f;
        for (int i = threadIdx.x; i < 2048; i += 256) wsf[WS_JOINT + i] = 0.f;
    }
    int gw = (blockIdx.x * blockDim.x + threadIdx.x) >> 6;
    int lane = threadIdx.x & 63;
    int wstr = (gridDim.x * blockDim.x) >> 6;
    for (int row = gw; row < NN + EE; row += wstr) {
        const float *x, *W0, *W1; float *t1, *sl; int r;
        if (row < NN) { r = row;      x = xn + (size_t)r * CNF; W0 = Wn0; W1 = Wn1; t1 = wsf + WS_T1N; sl = wsf + WS_SLINN; }
        else          { r = row - NN; x = xe + (size_t)r * CNF; W0 = We0; W1 = We1; t1 = wsf + WS_T1E; sl = wsf + WS_SLINE; }
        float4 xv = ((const float4*)x)[lane];
        float4 w0 = ((const float4*)W0)[lane];
        float4 w1 = ((const float4*)W1)[lane];
        float d0 = xv.x*w0.x + xv.y*w0.y + xv.z*w0.z + xv.w*w0.w;
        float d1 = xv.x*w1.x + xv.y*w1.y + xv.z*w1.z + xv.w*w1.w;
        #pragma unroll
        for (int o = 32; o > 0; o >>= 1) { d0 += __shfl_down(d0, o, 64); d1 += __shfl_down(d1, o, 64); }
        if (lane == 0) { t1[r] = d1; sl[r] = d0 + d1; }
    }
}

// =====================================================================
// Kernel B: conv-edge scatter, grid-wide.
// =====================================================================
__global__ void k_agg(const int* __restrict__ ein, const float* __restrict__ ewn,
                      const int* __restrict__ eie, const float* __restrict__ ewe,
                      float* __restrict__ wsf) {
    int i = blockIdx.x * blockDim.x + threadIdx.x;
    if (i < MN) {
        int s = ein[i], d = ein[MN + i];
        atomicAdd(wsf + WS_AGGN + d, ewn[i] * wsf[WS_T1N + s]);
    }
    if (i < ME) {
        int s = eie[i], d = eie[ME + i];
        atomicAdd(wsf + WS_AGGE + d, ewe[i] * wsf[WS_T1E + s]);
    }
}

// =====================================================================
// Kernel B2: grid-wide sigmoid scores + joint node score (order-indep
// pure atomicAdd into pre-zeroed joint).
// =====================================================================
__global__ void k_score(const int* __restrict__ ei,
                        const float* __restrict__ bn, const float* __restrict__ be,
                        float* __restrict__ wsf) {
    int i = blockIdx.x * blockDim.x + threadIdx.x;
    if (i < NN) {
        float z = wsf[WS_SLINN + i] - wsf[WS_AGGN + i] + bn[0];
        float s = 1.0f / (1.0f + expf(-z));
        wsf[WS_SCN + i] = s;
        atomicAdd(wsf + WS_JOINT + i, s);
    }
    if (i < EE) {
        float z = wsf[WS_SLINE + i] - wsf[WS_AGGE + i] + be[0];
        float s = 1.0f / (1.0f + expf(-z));
        wsf[WS_SCE + i] = s;
        float v = 0.125f * s;
        atomicAdd(wsf + WS_JOINT + ei[i], v);        // src (+1 in |B|)
        atomicAdd(wsf + WS_JOINT + ei[EE + i], v);   // dst (+1 in |B|; s==d -> 2x, matches ref)
    }
}

// --------------------------------------------------- block reduce, 1 barrier
// Write 16 wave-partials, barrier, all threads sum partials via broadcast
// reads. Caller must have a barrier between consecutive calls (s_red reuse).
__device__ __forceinline__ float block_reduce_sum_1b(float val, float* red) {
    #pragma unroll
    for (int o = 32; o > 0; o >>= 1) val += __shfl_down(val, o, 64);
    int lane = threadIdx.x & 63, wid = threadIdx.x >> 6;
    if (lane == 0) red[wid] = val;
    __syncthreads();
    float r = 0.0f;
    #pragma unroll
    for (int j = 0; j < 16; ++j) r += red[j];
    return r;
}

// --------------------------------------------------- block inclusive scan
__device__ __forceinline__ int block_incl_scan_1024(int v, int* t16) {
    int lane = threadIdx.x & 63, wid = threadIdx.x >> 6;
    int x = v;
    #pragma unroll
    for (int o = 1; o < 64; o <<= 1) {
        int t = __shfl_up(x, o, 64);
        if (lane >= o) x += t;
    }
    if (lane == 63) t16[wid] = x;
    __syncthreads();
    if (threadIdx.x < 16) {
        int w = t16[threadIdx.x];
        #pragma unroll
        for (int o = 1; o < 16; o <<= 1) {
            int t = __shfl_up(w, o, 16);
            if ((int)threadIdx.x >= o) w += t;
        }
        t16[threadIdx.x] = w;
    }
    __syncthreads();
    int base = wid ? t16[wid - 1] : 0;
    return base + x;
}

// =====================================================================
// Kernel C: block 0 = serial chain P5..P8 ONLY (P9 moved to k_final1
// where it overlaps the lam-independent output writes); blocks 1..255
// zero L0+L1+PM+XE+XE0 (322 MB, nontemporal).
// History: R1 single-wave P9 4x regression; R2 radix+scans -21; R3
// P3/P4 offload -18; R4 4-wave P9 +63; R5 per-wave hists +14; R6
// 4-pass P5 wash; R7 P9 1-barrier reduce + kept-only XE ~neutral ->
// phase-local levers exhausted, go structural.
// R8 (this): ADJE packs (nbr_rank<<14)|(e<<1)|dir so k_final1 can
// rebuild the power CSR without new workspace.
// =====================================================================
__global__ __launch_bounds__(1024) void k_mid(
        const int* __restrict__ ei,
        float* __restrict__ out, float* __restrict__ wsf, int* __restrict__ wsi) {
    int tid = threadIdx.x;
    if (blockIdx.x != 0) {
        // ------- zeroers: L1, PM, L0, XE, XE0 (nontemporal; no reuse pre-k_final) -------
        size_t w = (size_t)(blockIdx.x - 1) * 1024 + tid;
        size_t ws = (size_t)(gridDim.x - 1) * 1024;
        vf4 z = (vf4)(0.0f);
        vf4* l1 = (vf4*)(out + OUT_L1);
        for (size_t p = w; p < (size_t)EE * EE / 4; p += ws) __builtin_nontemporal_store(z, &l1[p]);
        vf4* pm = (vf4*)(out + OUT_PM);
        for (size_t p = w; p < (size_t)KK * EE / 4; p += ws) __builtin_nontemporal_store(z, &pm[p]);
        vf4* l0 = (vf4*)(out + OUT_L0);
        for (size_t p = w; p < (size_t)KK * KK / 4; p += ws) __builtin_nontemporal_store(z, &l0[p]);
        vf4* xe_ = (vf4*)(out + OUT_XE);
        for (size_t p = w; p < (size_t)EE * CNF / 4; p += ws) __builtin_nontemporal_store(z, &xe_[p]);
        vf4* xe0_ = (vf4*)(out + OUT_XE0);
        for (size_t p = w; p < (size_t)EE * CNF / 4; p += ws) __builtin_nontemporal_store(z, &xe0_[p]);
        return;
    }
    // ---------------- block 0: serial chain P5..P8, LDS-resident ----------------
    __shared__ unsigned long long s_u64[2048];       // 16 KB: bins / deg+scan+cur
    __shared__ unsigned short s_rank[2048];          // 4 KB
    __shared__ int s_t16[16];
    int* s_i = (int*)s_u64;                          // 4096 ints, phase-aliased

    // P5: top-K via exact radix select on 43-bit key (sortkey<<11)|(2047-i).
    unsigned long long k0, k1;
    {
        int i0 = 2 * tid, i1 = 2 * tid + 1;
        float f0 = wsf[WS_JOINT + i0], f1 = wsf[WS_JOINT + i1];
        unsigned u0 = __float_as_uint(f0), u1 = __float_as_uint(f1);
        unsigned sk0 = (u0 & 0x80000000u) ? ~u0 : (u0 | 0x80000000u);
        unsigned sk1 = (u1 & 0x80000000u) ? ~u1 : (u1 | 0x80000000u);
        k0 = (((unsigned long long)sk0) << 11) | (unsigned long long)(2047 - i0);
        k1 = (((unsigned long long)sk1) << 11) | (unsigned long long)(2047 - i1);
    }
    unsigned long long prefix = 0ULL;
    int rem = KK;
    #pragma unroll
    for (int p = 5; p >= 0; --p) {
        __syncthreads();                       // protect s_i reuse across passes
        if (tid < 256) s_i[tid] = 0;
        __syncthreads();
        int sh = p << 3;
        unsigned long long ph = prefix >> (sh + 8);
        if ((k0 >> (sh + 8)) == ph) atomicAdd(&s_i[(int)((k0 >> sh) & 255)], 1);
        if ((k1 >> (sh + 8)) == ph) atomicAdd(&s_i[(int)((k1 >> sh) & 255)], 1);
        __syncthreads();
        if (tid < 64) {                        // wave 0: boundary digit via suffix scan
            int b0 = s_i[4 * tid + 0], b1 = s_i[4 * tid + 1];
            int b2 = s_i[4 * tid + 2], b3 = s_i[4 * tid + 3];
            int sl = b0 + b1 + b2 + b3;
            int si = sl;
            #pragma unroll
            for (int o = 1; o < 64; o <<= 1) {
                int t = __shfl_down(si, o, 64);
                if (tid + o < 64) si += t;
            }
            int sup = si - sl;
            int sg3 = sup;
            int sg2 = sg3 + b3;
            int sg1 = sg2 + b2;
            int sg0 = sg1 + b1;
            if (sg0 < rem && rem <= sg0 + b0) { s_i[256] = (tid << 2) | 0; s_i[257] = rem - sg0; }
            if (sg1 < rem && rem <= sg1 + b1) { s_i[256] = (tid << 2) | 1; s_i[257] = rem - sg1; }
            if (sg2 < rem && rem <= sg2 + b2) { s_i[256] = (tid << 2) | 2; s_i[257] = rem - sg2; }
            if (sg3 < rem && rem <= sg3 + b3) { s_i[256] = (tid << 2) | 3; s_i[257] = rem - sg3; }
        }
        __syncthreads();
        prefix |= ((unsigned long long)(unsigned)s_i[256]) << sh;
        rem = s_i[257];
    }
    {
        int a0 = (k0 >= prefix) ? 1 : 0;
        int a1 = (k1 >= prefix) ? 1 : 0;
        int pr = a0 + a1;
        __syncthreads();
        int incl = block_incl_scan_1024(pr, s_t16);
        int excl = incl - pr;
        int i0 = 2 * tid, i1 = 2 * tid + 1;
        int r0 = excl, r1 = excl + a0;
        s_rank[i0] = a0 ? (unsigned short)r0 : (unsigned short)RBAD;
        s_rank[i1] = a1 ? (unsigned short)r1 : (unsigned short)RBAD;
        wsi[WS_RANK + i0] = a0 ? r0 : -1;
        wsi[WS_RANK + i1] = a1 ? r1 : -1;
        if (a0) wsi[WS_IDXK + r0] = i0;
        if (a1) wsi[WS_IDXK + r1] = i1;
    }
    __syncthreads();

    // P6: degrees (LDS s_i[0..1023]) + keep_e flags
    s_i[tid] = 0;
    __syncthreads();
    for (int e = tid; e < EE; e += 1024) {
        int s = ei[e], d = ei[EE + e];
        unsigned rs = s_rank[s], rd = s_rank[d];
        int kept = (rs != RBAD && rd != RBAD);
        wsi[WS_KEEPE + e] = kept;
        if (kept && s != d) {
            atomicAdd(&s_i[(int)rs], 1);
            atomicAdd(&s_i[(int)rd], 1);
        }
    }
    __syncthreads();

    // P7: CSR offsets via shfl block scan; cur in s_i[2048..3071]
    {
        int dg = s_i[tid];
        int incl = block_incl_scan_1024(dg, s_t16);
        int offs = incl - dg;
        s_i[2048 + tid] = offs;                // cur
        wsi[WS_OFFS + tid] = offs;
        if (tid == 1023) wsi[WS_OFFS + 1024] = incl;
    }
    __syncthreads();

    // P8: CSR fill -> global only, PACKED: (nbr_rank<<14)|(e<<1)|dir
    for (int e = tid; e < EE; e += 1024) {
        int s = ei[e], d = ei[EE + e];
        unsigned rs = s_rank[s], rd = s_rank[d];
        if (rs != RBAD && rd != RBAD && s != d) {
            int p = atomicAdd(&s_i[2048 + (int)rs], 1);
            wsi[WS_ADJE + p] = ((int)rd << 14) | (e << 1);
            int q = atomicAdd(&s_i[2048 + (int)rd], 1);
            wsi[WS_ADJE + q] = ((int)rs << 14) | (e << 1) | 1;
        }
    }
}

// =====================================================================
// Kernel D1: block 0 = P9 power iteration (CSR rebuilt from packed
// ADJE into LDS; numerically identical to the r3/r7 P9); blocks 1..255
// concurrently stream every lam-INDEPENDENT output: (a) XN/XN0 gathers,
// (b) kept XE/XE0 rows, (e) PM +-1 writes. P9 (~50us) hides them.
// =====================================================================
__global__ __launch_bounds__(1024) void k_final1(
        const float* __restrict__ xn, const float* __restrict__ xe,
        const float* __restrict__ xn0, const float* __restrict__ xe0,
        const int* __restrict__ ei,
        float* __restrict__ out, float* __restrict__ wsf,
        const int* __restrict__ wsi) {
    __shared__ unsigned short s_adjo[16384];   // 32 KB
    __shared__ float s_v0[1024], s_v1[1024];   // 8 KB
    __shared__ float s_red[16];
    int tid = threadIdx.x;

    if (blockIdx.x == 0) {
        // -------- P9: power iteration for lambda_max (16 waves, 1 node/thread) --------
        int total = wsi[WS_OFFS + 1024];
        for (int i = tid; i < total; i += 1024)
            s_adjo[i] = (unsigned short)(((unsigned)wsi[WS_ADJE + i]) >> 14);
        int o0 = wsi[WS_OFFS + tid];
        int d  = wsi[WS_OFFS + tid + 1] - o0;
        unsigned h = (unsigned)tid * 2654435761u + 911u;
        h ^= h >> 15; h *= 2246822519u; h ^= h >> 13;
        s_v0[tid] = (float)(h & 0xFFFFu) * (1.0f / 65536.0f) - 0.5f;
        __syncthreads();
        int aj[DCAP];
        #pragma unroll
        for (int j = 0; j < DCAP; ++j) aj[j] = (j < d) ? (int)s_adjo[o0 + j] : 0;
        float* vc = s_v0; float* vn = s_v1;
        for (int iter = 0; iter < PWR_T; ++iter) {
            float acc = 0.0f;
            #pragma unroll
            for (int j = 0; j < DCAP; ++j) acc += (j < d) ? vc[aj[j]] : 0.0f;
            for (int i = o0 + DCAP; i < o0 + d; ++i) acc += vc[(int)s_adjo[i]];
            float y = (float)d * vc[tid] - acc;
            if ((iter & 7) == 7) {
                float n2 = block_reduce_sum_1b(y * y, s_red);
                y *= (n2 > 0.0f) ? rsqrtf(n2) : 0.0f;
            }
            vn[tid] = y;
            __syncthreads();
            float* tmp = vc; vc = vn; vn = tmp;
        }
        float acc = 0.0f;
        #pragma unroll
        for (int j = 0; j < DCAP; ++j) acc += (j < d) ? vc[aj[j]] : 0.0f;
        for (int i = o0 + DCAP; i < o0 + d; ++i) acc += vc[(int)s_adjo[i]];
        float y = (float)d * vc[tid] - acc;
        float rq = block_reduce_sum_1b(vc[tid] * y, s_red);
        if (tid == 0) wsf[WS_LAM] = rq;
        return;
    }

    // -------- blocks 1..255: lam-independent output streams --------
    int gt = (blockIdx.x - 1) * 1024 + tid;
    int gstr = (gridDim.x - 1) * 1024;

    // (a) kept-node feature gathers (rows fully overwritten, no pre-zero)
    for (int i = gt; i < KK * 64; i += gstr) {
        int r = i >> 6, c = i & 63;
        int src = wsi[WS_IDXK + r];
        float s = wsf[WS_SCN + src];
        float4 v = ((const float4*)(xn + (size_t)src * CNF))[c];
        v.x *= s; v.y *= s; v.z *= s; v.w *= s;
        ((float4*)(out + OUT_XN))[(size_t)r * 64 + c] = v;
        ((float4*)(out + OUT_XN0))[(size_t)r * 64 + c] = ((const float4*)(xn0 + (size_t)src * CNF))[c];
    }
    // (b) edge feature rows, KEPT ONLY (dropped rows zeroed by k_mid zeroers);
    // wave-uniform skip: each wave owns one 256-float row.
    for (int i = gt; i < EE * 64; i += gstr) {
        int e = i >> 6;
        if (!wsi[WS_KEEPE + e]) continue;
        int c = i & 63;
        float s = wsf[WS_SCE + e];
        float4 v = ((const float4*)(xe + (size_t)e * CNF))[c];
        v.x *= s; v.y *= s; v.z *= s; v.w *= s;
        ((float4*)(out + OUT_XE))[(size_t)e * 64 + c] = v;
        ((float4*)(out + OUT_XE0))[(size_t)e * 64 + c] = ((const float4*)(xe0 + (size_t)e * CNF))[c];
    }
    // (e) par_masked +-1 writes (pre-zeroed; lam-independent)
    {
        float* pm = out + OUT_PM;
        for (int e = gt; e < EE; e += gstr) {
            int s = ei[e], d = ei[EE + e];
            int rs = wsi[WS_RANK + s], rd = wsi[WS_RANK + d];
            if (rs < 0 || rd < 0 || s == d) continue;
            pm[(size_t)rs * EE + e] = -1.0f;
            pm[(size_t)rd * EE + e] =  1.0f;
        }
    }
}

// =====================================================================
// Kernel D2: lam-scaled scatters only (L0, L1). Small.
// =====================================================================
__global__ __launch_bounds__(1024) void k_final2(
        const int* __restrict__ ei,
        float* __restrict__ out, const float* __restrict__ wsf,
        const int* __restrict__ wsi) {
    float sc = 2.0f / wsf[WS_LAM];
    int gt = blockIdx.x * 1024 + threadIdx.x;
    int gstr = gridDim.x * 1024;

    // (c) L0 scatter (pre-zeroed in k_mid)
    {
        float* L0 = out + OUT_L0;
        for (int e = gt; e < EE; e += gstr) {
            int s = ei[e], d = ei[EE + e];
            int rs = wsi[WS_RANK + s], rd = wsi[WS_RANK + d];
            if (rs < 0 || rd < 0 || s == d) continue;
            atomicAdd(&L0[(size_t)rs * KK + rs],  sc);
            atomicAdd(&L0[(size_t)rd * KK + rd],  sc);
            atomicAdd(&L0[(size_t)rs * KK + rd], -sc);
            atomicAdd(&L0[(size_t)rd * KK + rs], -sc);
        }
    }
    // (d) L1 scatter: wave per node-row, lanes over inner pairs.
    // ADJE packed: e = (v>>1)&0x1FFF, dir = v&1.
    {
        float* L1 = out + OUT_L1;
        int gwv = gt >> 6, lane = gt & 63, wstr = gstr >> 6;
        for (int r = gwv; r < KK; r += wstr) {
            int o0 = wsi[WS_OFFS + r], o1 = wsi[WS_OFFS + r + 1];
            for (int i = o0; i < o1; ++i) {
                int eiv = wsi[WS_ADJE + i];
                int e = (eiv >> 1) & 0x1FFF;
                float si = (eiv & 1) ? sc : -sc;
                for (int j = o0 + lane; j < o1; j += 64) {
                    int ejv = wsi[WS_ADJE + j];
                    atomicAdd(&L1[(size_t)e * EE + ((ejv >> 1) & 0x1FFF)], (ejv & 1) ? si : -si);
                }
            }
        }
    }
}

extern "C" void kernel_launch(void* const* d_in, const int* in_sizes, int n_in,
                              void* d_out, int out_size, void* d_ws, size_t ws_size,
                              hipStream_t stream) {
    const float* x_n  = (const float*)d_in[0];
    const int*   ei_n = (const int*)  d_in[1];
    const float* ew_n = (const float*)d_in[2];
    const float* x_e  = (const float*)d_in[3];
    const int*   ei_e = (const int*)  d_in[4];
    const float* ew_e = (const float*)d_in[5];
    const int*   ei   = (const int*)  d_in[6];
    const float* x_n0 = (const float*)d_in[9];
    const float* x_e0 = (const float*)d_in[10];
    const float* Wn0  = (const float*)d_in[11];
    const float* Wn1  = (const float*)d_in[12];
    const float* bn   = (const float*)d_in[13];
    const float* We0  = (const float*)d_in[14];
    const float* We1  = (const float*)d_in[15];
    const float* be   = (const float*)d_in[16];

    float* out = (float*)d_out;
    float* wsf = (float*)d_ws;
    int*   wsi = (int*)d_ws;

    k_prep  <<<640, 256, 0, stream>>>(x_n, x_e, Wn0, Wn1, We0, We1, wsf);
    k_agg   <<<256, 256, 0, stream>>>(ei_n, ew_n, ei_e, ew_e, wsf);
    k_score <<<32, 256, 0, stream>>>(ei, bn, be, wsf);
    k_mid   <<<256, 1024, 0, stream>>>(ei, out, wsf, wsi);
    k_final1<<<256, 1024, 0, stream>>>(x_n, x_e, x_n0, x_e0, ei, out, wsf, wsi);
    k_final2<<<256, 1024, 0, stream>>>(ei, out, wsf, wsi);
}

// Round 9
// 428.425 us; speedup vs baseline: 1.0774x; 1.0774x over previous
//
#include <hip/hip_runtime.h>
#include <math.h>

// Problem constants
#define NN   2048
#define EE   8192
#define CNF  256
#define MN   16384
#define ME   65536
#define KK   1024

// Output layout (float element offsets)
#define OUT_XN   ((size_t)0)
#define OUT_L0   ((size_t)262144)
#define OUT_XE   ((size_t)1310720)
#define OUT_L1   ((size_t)3407872)
#define OUT_PM   ((size_t)70516736)
#define OUT_XN0  ((size_t)78905344)
#define OUT_XE0  ((size_t)79167488)

// Workspace layout (element offsets)
#define WS_T1N    0
#define WS_SLINN  2048
#define WS_T1E    4096
#define WS_SLINE  12288
#define WS_SCN    20480
#define WS_SCE    22528
#define WS_JOINT  30720   // dead gap 30720..32767 (2048 floats) — no ws growth
#define WS_AGGN   32768
#define WS_AGGE   34816
#define WS_LAM    43008
#define WS_IDXK   43520
#define WS_RANK   44544
#define WS_OFFS   47616
#define WS_ADJE   66176   // int[16384]: (e<<1)|dir
#define WS_KEEPE  82560   // int[8192]

#define DCAP  8
#define PWR_T 56          // 64->56: err ~ (lam2/lam1)^112; lam feeds 0.05-scale
                          // entries, 1e-3 rel lam err -> 5e-5 abs, 100x under absmax
#define RBAD  0xFFFFu

// native vector for nontemporal builtin (HIP float4 is a class -> rejected)
typedef float vf4 __attribute__((ext_vector_type(4)));

// =====================================================================
// Kernel A: row dots (wave per row) + zero the ws accumulators.
// =====================================================================
__global__ void k_prep(const float* __restrict__ xn, const float* __restrict__ xe,
                       const float* __restrict__ Wn0, const float* __restrict__ Wn1,
                       const float* __restrict__ We0, const float* __restrict__ We1,
                       float* __restrict__ wsf) {
    if (blockIdx.x == 0) {   // zero accumulators (AGGN, AGGE) + joint
        for (int i = threadIdx.x; i < 2048; i += 256) wsf[WS_AGGN + i] = 0.f;
        for (int i = threadIdx.x; i < 8192; i += 256) wsf[WS_AGGE + i] = 0.f;
        for (int i = threadIdx.x; i < 2048; i += 256) wsf[WS_JOINT + i] = 0.f;
    }
    int gw = (blockIdx.x * blockDim.x + threadIdx.x) >> 6;
    int lane = threadIdx.x & 63;
    int wstr = (gridDim.x * blockDim.x) >> 6;
    for (int row = gw; row < NN + EE; row += wstr) {
        const float *x, *W0, *W1; float *t1, *sl; int r;
        if (row < NN) { r = row;      x = xn + (size_t)r * CNF; W0 = Wn0; W1 = Wn1; t1 = wsf + WS_T1N; sl = wsf + WS_SLINN; }
        else          { r = row - NN; x = xe + (size_t)r * CNF; W0 = We0; W1 = We1; t1 = wsf + WS_T1E; sl = wsf + WS_SLINE; }
        float4 xv = ((const float4*)x)[lane];
        float4 w0 = ((const float4*)W0)[lane];
        float4 w1 = ((const float4*)W1)[lane];
        float d0 = xv.x*w0.x + xv.y*w0.y + xv.z*w0.z + xv.w*w0.w;
        float d1 = xv.x*w1.x + xv.y*w1.y + xv.z*w1.z + xv.w*w1.w;
        #pragma unroll
        for (int o = 32; o > 0; o >>= 1) { d0 += __shfl_down(d0, o, 64); d1 += __shfl_down(d1, o, 64); }
        if (lane == 0) { t1[r] = d1; sl[r] = d0 + d1; }
    }
}

// =====================================================================
// Kernel B: conv-edge scatter, grid-wide.
// =====================================================================
__global__ void k_agg(const int* __restrict__ ein, const float* __restrict__ ewn,
                      const int* __restrict__ eie, const float* __restrict__ ewe,
                      float* __restrict__ wsf) {
    int i = blockIdx.x * blockDim.x + threadIdx.x;
    if (i < MN) {
        int s = ein[i], d = ein[MN + i];
        atomicAdd(wsf + WS_AGGN + d, ewn[i] * wsf[WS_T1N + s]);
    }
    if (i < ME) {
        int s = eie[i], d = eie[ME + i];
        atomicAdd(wsf + WS_AGGE + d, ewe[i] * wsf[WS_T1E + s]);
    }
}

// =====================================================================
// Kernel B2: grid-wide sigmoid scores + joint node score (order-indep
// pure atomicAdd into pre-zeroed joint).
// =====================================================================
__global__ void k_score(const int* __restrict__ ei,
                        const float* __restrict__ bn, const float* __restrict__ be,
                        float* __restrict__ wsf) {
    int i = blockIdx.x * blockDim.x + threadIdx.x;
    if (i < NN) {
        float z = wsf[WS_SLINN + i] - wsf[WS_AGGN + i] + bn[0];
        float s = 1.0f / (1.0f + expf(-z));
        wsf[WS_SCN + i] = s;
        atomicAdd(wsf + WS_JOINT + i, s);
    }
    if (i < EE) {
        float z = wsf[WS_SLINE + i] - wsf[WS_AGGE + i] + be[0];
        float s = 1.0f / (1.0f + expf(-z));
        wsf[WS_SCE + i] = s;
        float v = 0.125f * s;
        atomicAdd(wsf + WS_JOINT + ei[i], v);        // src (+1 in |B|)
        atomicAdd(wsf + WS_JOINT + ei[EE + i], v);   // dst (+1 in |B|; s==d -> 2x, matches ref)
    }
}

// --------------------------------------------------- block reduce, 1 barrier
// Write 16 wave-partials, barrier, all threads sum partials via broadcast
// reads. Caller must have a barrier between consecutive calls (s_red reuse).
__device__ __forceinline__ float block_reduce_sum_1b(float val, float* red) {
    #pragma unroll
    for (int o = 32; o > 0; o >>= 1) val += __shfl_down(val, o, 64);
    int lane = threadIdx.x & 63, wid = threadIdx.x >> 6;
    if (lane == 0) red[wid] = val;
    __syncthreads();
    float r = 0.0f;
    #pragma unroll
    for (int j = 0; j < 16; ++j) r += red[j];
    return r;
}

// --------------------------------------------------- block inclusive scan
__device__ __forceinline__ int block_incl_scan_1024(int v, int* t16) {
    int lane = threadIdx.x & 63, wid = threadIdx.x >> 6;
    int x = v;
    #pragma unroll
    for (int o = 1; o < 64; o <<= 1) {
        int t = __shfl_up(x, o, 64);
        if (lane >= o) x += t;
    }
    if (lane == 63) t16[wid] = x;
    __syncthreads();
    if (threadIdx.x < 16) {
        int w = t16[threadIdx.x];
        #pragma unroll
        for (int o = 1; o < 16; o <<= 1) {
            int t = __shfl_up(w, o, 16);
            if ((int)threadIdx.x >= o) w += t;
        }
        t16[threadIdx.x] = w;
    }
    __syncthreads();
    int base = wid ? t16[wid - 1] : 0;
    return base + x;
}

// =====================================================================
// Kernel C: block 0 = serial chain P5..P9, fully LDS-resident;
// blocks 1..255 zero L0+L1+PM+XE+XE0 (322 MB, nontemporal) meanwhile.
// FROZEN LESSONS: P9 stays HERE, 16 waves, 1 node/thread, DCAP preload
// (R1 single-wave 4x regress; R4 4-wave +63; R8 P9-in-k_final overlap
// +30 — co-resident streaming waves starve the barrier chain).
// R5: per-wave hists +14 (same-addr LDS atomics are fine). R6: 4-pass
// P5 wash. R7 (this base): 1-barrier P9 reduce + kept-only XE = 432us.
// R9 (this): P6/P8 register-cache fusion (each thread owns the same 8
// edges in both passes -> pk[8] regs kill P8's ei re-read + rank LDS
// lookups); PWR_T 64->56.
// =====================================================================
__global__ __launch_bounds__(1024) void k_mid(
        const int* __restrict__ ei,
        float* __restrict__ out, float* __restrict__ wsf, int* __restrict__ wsi) {
    int tid = threadIdx.x;
    if (blockIdx.x != 0) {
        // ------- zeroers: L1, PM, L0, XE, XE0 (nontemporal; no reuse pre-k_final) -------
        size_t w = (size_t)(blockIdx.x - 1) * 1024 + tid;
        size_t ws = (size_t)(gridDim.x - 1) * 1024;
        vf4 z = (vf4)(0.0f);
        vf4* l1 = (vf4*)(out + OUT_L1);
        for (size_t p = w; p < (size_t)EE * EE / 4; p += ws) __builtin_nontemporal_store(z, &l1[p]);
        vf4* pm = (vf4*)(out + OUT_PM);
        for (size_t p = w; p < (size_t)KK * EE / 4; p += ws) __builtin_nontemporal_store(z, &pm[p]);
        vf4* l0 = (vf4*)(out + OUT_L0);
        for (size_t p = w; p < (size_t)KK * KK / 4; p += ws) __builtin_nontemporal_store(z, &l0[p]);
        vf4* xe_ = (vf4*)(out + OUT_XE);
        for (size_t p = w; p < (size_t)EE * CNF / 4; p += ws) __builtin_nontemporal_store(z, &xe_[p]);
        vf4* xe0_ = (vf4*)(out + OUT_XE0);
        for (size_t p = w; p < (size_t)EE * CNF / 4; p += ws) __builtin_nontemporal_store(z, &xe0_[p]);
        return;
    }
    // ---------------- block 0: serial chain, LDS-resident ----------------
    __shared__ unsigned long long s_u64[2048];       // 16 KB: bins / deg+scan+cur / power v
    __shared__ unsigned short s_rank[2048];          // 4 KB
    __shared__ unsigned short s_adjo[16384 + DCAP];  // 32 KB (+pad for reg-preload)
    __shared__ float s_red[16];
    __shared__ int s_t16[16];
    int* s_i = (int*)s_u64;                          // 4096 ints, phase-aliased

    // P5: top-K via exact radix select on 43-bit key (sortkey<<11)|(2047-i).
    unsigned long long k0, k1;
    {
        int i0 = 2 * tid, i1 = 2 * tid + 1;
        float f0 = wsf[WS_JOINT + i0], f1 = wsf[WS_JOINT + i1];
        unsigned u0 = __float_as_uint(f0), u1 = __float_as_uint(f1);
        unsigned sk0 = (u0 & 0x80000000u) ? ~u0 : (u0 | 0x80000000u);
        unsigned sk1 = (u1 & 0x80000000u) ? ~u1 : (u1 | 0x80000000u);
        k0 = (((unsigned long long)sk0) << 11) | (unsigned long long)(2047 - i0);
        k1 = (((unsigned long long)sk1) << 11) | (unsigned long long)(2047 - i1);
    }
    unsigned long long prefix = 0ULL;
    int rem = KK;
    #pragma unroll
    for (int p = 5; p >= 0; --p) {
        __syncthreads();                       // protect s_i reuse across passes
        if (tid < 256) s_i[tid] = 0;
        __syncthreads();
        int sh = p << 3;
        unsigned long long ph = prefix >> (sh + 8);
        if ((k0 >> (sh + 8)) == ph) atomicAdd(&s_i[(int)((k0 >> sh) & 255)], 1);
        if ((k1 >> (sh + 8)) == ph) atomicAdd(&s_i[(int)((k1 >> sh) & 255)], 1);
        __syncthreads();
        if (tid < 64) {                        // wave 0: boundary digit via suffix scan
            int b0 = s_i[4 * tid + 0], b1 = s_i[4 * tid + 1];
            int b2 = s_i[4 * tid + 2], b3 = s_i[4 * tid + 3];
            int sl = b0 + b1 + b2 + b3;
            int si = sl;
            #pragma unroll
            for (int o = 1; o < 64; o <<= 1) {
                int t = __shfl_down(si, o, 64);
                if (tid + o < 64) si += t;
            }
            int sup = si - sl;                 // count with digit-group > this lane
            int sg3 = sup;
            int sg2 = sg3 + b3;
            int sg1 = sg2 + b2;
            int sg0 = sg1 + b1;
            if (sg0 < rem && rem <= sg0 + b0) { s_i[256] = (tid << 2) | 0; s_i[257] = rem - sg0; }
            if (sg1 < rem && rem <= sg1 + b1) { s_i[256] = (tid << 2) | 1; s_i[257] = rem - sg1; }
            if (sg2 < rem && rem <= sg2 + b2) { s_i[256] = (tid << 2) | 2; s_i[257] = rem - sg2; }
            if (sg3 < rem && rem <= sg3 + b3) { s_i[256] = (tid << 2) | 3; s_i[257] = rem - sg3; }
        }
        __syncthreads();
        prefix |= ((unsigned long long)(unsigned)s_i[256]) << sh;
        rem = s_i[257];
    }
    {
        int a0 = (k0 >= prefix) ? 1 : 0;
        int a1 = (k1 >= prefix) ? 1 : 0;
        int pr = a0 + a1;
        __syncthreads();                       // s_i[256..257] reads done before t16/s_i reuse
        int incl = block_incl_scan_1024(pr, s_t16);
        int excl = incl - pr;
        int i0 = 2 * tid, i1 = 2 * tid + 1;
        int r0 = excl, r1 = excl + a0;
        s_rank[i0] = a0 ? (unsigned short)r0 : (unsigned short)RBAD;
        s_rank[i1] = a1 ? (unsigned short)r1 : (unsigned short)RBAD;
        wsi[WS_RANK + i0] = a0 ? r0 : -1;      // for k_final
        wsi[WS_RANK + i1] = a1 ? r1 : -1;
        if (a0) wsi[WS_IDXK + r0] = i0;
        if (a1) wsi[WS_IDXK + r1] = i1;
    }
    __syncthreads();

    // P6: degrees + keep_e; edge data cached in pk[8] regs for P8
    // (each thread owns e = tid + 1024k in BOTH passes; full unroll ->
    // static reg indexing, rule #20 safe)
    int pk[8];
    s_i[tid] = 0;
    __syncthreads();
    #pragma unroll
    for (int k = 0; k < 8; ++k) {
        int e = tid + (k << 10);
        int s = ei[e], d = ei[EE + e];
        unsigned rs = s_rank[s], rd = s_rank[d];
        int kept = (rs != RBAD && rd != RBAD);
        wsi[WS_KEEPE + e] = kept;
        pk[k] = -1;
        if (kept && s != d) {
            pk[k] = (int)rs | ((int)rd << 12);
            atomicAdd(&s_i[(int)rs], 1);
            atomicAdd(&s_i[(int)rd], 1);
        }
    }
    __syncthreads();

    // P7: CSR offsets via shfl block scan; cur in s_i[2048..3071]
    {
        int dg = s_i[tid];
        int incl = block_incl_scan_1024(dg, s_t16);
        int offs = incl - dg;
        s_i[2048 + tid] = offs;                // cur
        wsi[WS_OFFS + tid] = offs;             // for k_final + power
        if (tid == 1023) wsi[WS_OFFS + 1024] = incl;
    }
    __syncthreads();

    // P8: CSR fill from cached regs (no ei re-read, no rank lookups)
    #pragma unroll
    for (int k = 0; k < 8; ++k) {
        if (pk[k] >= 0) {
            int e = tid + (k << 10);
            int rs = pk[k] & 0xFFF, rd = (pk[k] >> 12) & 0xFFF;
            int p = atomicAdd(&s_i[2048 + rs], 1);
            s_adjo[p] = (unsigned short)rd;
            wsi[WS_ADJE + p] = (e << 1);
            int q = atomicAdd(&s_i[2048 + rd], 1);
            s_adjo[q] = (unsigned short)rs;
            wsi[WS_ADJE + q] = (e << 1) | 1;
        }
    }
    __syncthreads();

    // P9: power iteration — 16 waves, 1 node/thread, DCAP reg-preload
    // (v aliases s_i[0..2047] as floats; offs read from GLOBAL before
    // v-init to avoid alias hazard). 1-barrier reduce.
    {
        int o0 = wsi[WS_OFFS + tid];
        int d  = wsi[WS_OFFS + tid + 1] - o0;
        __syncthreads();
        float* v0 = (float*)s_u64;
        float* v1 = v0 + 1024;
        unsigned h = (unsigned)tid * 2654435761u + 911u;
        h ^= h >> 15; h *= 2246822519u; h ^= h >> 13;
        v0[tid] = (float)(h & 0xFFFFu) * (1.0f / 65536.0f) - 0.5f;
        int aj[DCAP];
        #pragma unroll
        for (int j = 0; j < DCAP; ++j) aj[j] = (j < d) ? (int)s_adjo[o0 + j] : 0;
        __syncthreads();
        float* vc = v0; float* vn = v1;
        for (int iter = 0; iter < PWR_T; ++iter) {
            float acc = 0.0f;
            #pragma unroll
            for (int j = 0; j < DCAP; ++j) acc += (j < d) ? vc[aj[j]] : 0.0f;
            for (int i = o0 + DCAP; i < o0 + d; ++i) acc += vc[(int)s_adjo[i]];
            float y = (float)d * vc[tid] - acc;
            if ((iter & 7) == 7) {
                float n2 = block_reduce_sum_1b(y * y, s_red);
                y *= (n2 > 0.0f) ? rsqrtf(n2) : 0.0f;
            }
            vn[tid] = y;
            __syncthreads();
            float* tmp = vc; vc = vn; vn = tmp;
        }
        float acc = 0.0f;
        #pragma unroll
        for (int j = 0; j < DCAP; ++j) acc += (j < d) ? vc[aj[j]] : 0.0f;
        for (int i = o0 + DCAP; i < o0 + d; ++i) acc += vc[(int)s_adjo[i]];
        float y = (float)d * vc[tid] - acc;
        float rq = block_reduce_sum_1b(vc[tid] * y, s_red);
        if (tid == 0) wsf[WS_LAM] = rq;
    }
}

// =====================================================================
// Kernel D: all output writes that depend on the chain (2/lam folded).
// (b) writes ONLY kept edge rows — dropped rows pre-zeroed by k_mid.
// =====================================================================
__global__ __launch_bounds__(1024) void k_final(
        const float* __restrict__ xn, const float* __restrict__ xe,
        const float* __restrict__ xn0, const float* __restrict__ xe0,
        const int* __restrict__ ei,
        float* __restrict__ out, const float* __restrict__ wsf,
        const int* __restrict__ wsi) {
    float sc = 2.0f / wsf[WS_LAM];
    int gt = blockIdx.x * 1024 + threadIdx.x;
    int gstr = gridDim.x * 1024;

    // (a) kept-node feature gathers (rows fully overwritten, no pre-zero)
    for (int i = gt; i < KK * 64; i += gstr) {
        int r = i >> 6, c = i & 63;
        int src = wsi[WS_IDXK + r];
        float s = wsf[WS_SCN + src];
        float4 v = ((const float4*)(xn + (size_t)src * CNF))[c];
        v.x *= s; v.y *= s; v.z *= s; v.w *= s;
        ((float4*)(out + OUT_XN))[(size_t)r * 64 + c] = v;
        ((float4*)(out + OUT_XN0))[(size_t)r * 64 + c] = ((const float4*)(xn0 + (size_t)src * CNF))[c];
    }
    // (b) edge feature rows, KEPT ONLY (dropped rows zeroed by k_mid zeroers);
    // wave-uniform skip: each wave owns one 256-float row.
    for (int i = gt; i < EE * 64; i += gstr) {
        int e = i >> 6;
        if (!wsi[WS_KEEPE + e]) continue;
        int c = i & 63;
        float s = wsf[WS_SCE + e];
        float4 v = ((const float4*)(xe + (size_t)e * CNF))[c];
        v.x *= s; v.y *= s; v.z *= s; v.w *= s;
        ((float4*)(out + OUT_XE))[(size_t)e * 64 + c] = v;
        ((float4*)(out + OUT_XE0))[(size_t)e * 64 + c] = ((const float4*)(xe0 + (size_t)e * CNF))[c];
    }
    // (c) par_masked + L0 scatter (pre-zeroed in k_mid)
    {
        float* pm = out + OUT_PM;
        float* L0 = out + OUT_L0;
        for (int e = gt; e < EE; e += gstr) {
            int s = ei[e], d = ei[EE + e];
            int rs = wsi[WS_RANK + s], rd = wsi[WS_RANK + d];
            if (rs < 0 || rd < 0 || s == d) continue;
            pm[(size_t)rs * EE + e] = -1.0f;
            pm[(size_t)rd * EE + e] =  1.0f;
            atomicAdd(&L0[(size_t)rs * KK + rs],  sc);
            atomicAdd(&L0[(size_t)rd * KK + rd],  sc);
            atomicAdd(&L0[(size_t)rs * KK + rd], -sc);
            atomicAdd(&L0[(size_t)rd * KK + rs], -sc);
        }
    }
    // (d) L1 scatter: wave per node-row, lanes over inner pairs
    {
        float* L1 = out + OUT_L1;
        int gwv = gt >> 6, lane = gt & 63, wstr = gstr >> 6;
        for (int r = gwv; r < KK; r += wstr) {
            int o0 = wsi[WS_OFFS + r], o1 = wsi[WS_OFFS + r + 1];
            for (int i = o0; i < o1; ++i) {
                int eiv = wsi[WS_ADJE + i];
                int e = eiv >> 1;
                float si = (eiv & 1) ? sc : -sc;
                for (int j = o0 + lane; j < o1; j += 64) {
                    int ejv = wsi[WS_ADJE + j];
                    atomicAdd(&L1[(size_t)e * EE + (ejv >> 1)], (ejv & 1) ? si : -si);
                }
            }
        }
    }
}

extern "C" void kernel_launch(void* const* d_in, const int* in_sizes, int n_in,
                              void* d_out, int out_size, void* d_ws, size_t ws_size,
                              hipStream_t stream) {
    const float* x_n  = (const float*)d_in[0];
    const int*   ei_n = (const int*)  d_in[1];
    const float* ew_n = (const float*)d_in[2];
    const float* x_e  = (const float*)d_in[3];
    const int*   ei_e = (const int*)  d_in[4];
    const float* ew_e = (const float*)d_in[5];
    const int*   ei   = (const int*)  d_in[6];
    const float* x_n0 = (const float*)d_in[9];
    const float* x_e0 = (const float*)d_in[10];
    const float* Wn0  = (const float*)d_in[11];
    const float* Wn1  = (const float*)d_in[12];
    const float* bn   = (const float*)d_in[13];
    const float* We0  = (const float*)d_in[14];
    const float* We1  = (const float*)d_in[15];
    const float* be   = (const float*)d_in[16];

    float* out = (float*)d_out;
    float* wsf = (float*)d_ws;
    int*   wsi = (int*)d_ws;

    k_prep <<<640, 256, 0, stream>>>(x_n, x_e, Wn0, Wn1, We0, We1, wsf);
    k_agg  <<<256, 256, 0, stream>>>(ei_n, ew_n, ei_e, ew_e, wsf);
    k_score<<<32, 256, 0, stream>>>(ei, bn, be, wsf);
    k_mid  <<<256, 1024, 0, stream>>>(ei, out, wsf, wsi);
    k_final<<<256, 1024, 0, stream>>>(x_n, x_e, x_n0, x_e0, ei, out, wsf, wsi);
}